// Round 4
// baseline (624.128 us; speedup 1.0000x reference)
//
#include <hip/hip_runtime.h>

// ---------------- constants ----------------
#define BB   512   // batch
#define SS   256   // seq len
#define EE   128   // emb dim
#define HH   128   // per-dir hidden
#define LL   59    // labels
#define STARTL 57
#define STOPL  58
#define VOCAB 50000

typedef float  f32x4  __attribute__((ext_vector_type(4)));
typedef short  bf16x8 __attribute__((ext_vector_type(8)));
typedef short  s16x4  __attribute__((ext_vector_type(4)));

__device__ __forceinline__ short f2bf(float f) {
    unsigned u = __float_as_uint(f);
    u += 0x7FFFu + ((u >> 16) & 1u);   // RNE
    return (short)(u >> 16);
}
__device__ __forceinline__ float bf2f(unsigned short s) {
    return __uint_as_float(((unsigned)s) << 16);
}
__device__ __forceinline__ float sigf(float x) {
    float e = __builtin_amdgcn_exp2f(-1.44269504f * x);
    return __builtin_amdgcn_rcpf(1.0f + e);
}
__device__ __forceinline__ float tanhf_(float x) {
    float e = __builtin_amdgcn_exp2f(2.88539008f * x);
    return 1.0f - 2.0f * __builtin_amdgcn_rcpf(e + 1.0f);
}
__device__ __forceinline__ float wmax64(float v) {
    #pragma unroll
    for (int o = 32; o; o >>= 1) v = fmaxf(v, __shfl_xor(v, o));
    return v;
}
__device__ __forceinline__ float wsum64(float v) {
    #pragma unroll
    for (int o = 32; o; o >>= 1) v += __shfl_xor(v, o);
    return v;
}
// LDS-only barrier: global ops stay in flight across it.
__device__ __forceinline__ void bar_lds() {
    asm volatile("s_waitcnt lgkmcnt(0)\n\ts_barrier" ::: "memory");
}
// unpack 4 packed bf16 (from 2 ints) into f32x4
__device__ __forceinline__ void unpk(int a, int b, f32x4& o) {
    o[0] = __uint_as_float((unsigned)a << 16);
    o[1] = __uint_as_float((unsigned)a & 0xFFFF0000u);
    o[2] = __uint_as_float((unsigned)b << 16);
    o[3] = __uint_as_float((unsigned)b & 0xFFFF0000u);
}

// ---------------- kernel 0: f32 -> bf16 tables (+ bias sums) ----------------
__global__ __launch_bounds__(256) void conv_k(
    const float* __restrict__ embed,
    const float* __restrict__ Wih_f, const float* __restrict__ Wih_b,
    const float* __restrict__ bih_f, const float* __restrict__ bhh_f,
    const float* __restrict__ bih_b, const float* __restrict__ bhh_b,
    unsigned short* __restrict__ ebf, unsigned short* __restrict__ wix,
    float* __restrict__ bsum, int full)
{
    const int W1 = VOCAB * EE / 4;              // 1,600,000 float4 of embed
    const int W2 = W1 + (full ? 2 * 16384 : 0); // wix float4 (65536/4 per dir)
    const int W3 = W2 + (full ? 1024 : 0);      // bias sums
    for (int i = blockIdx.x * blockDim.x + threadIdx.x; i < W3;
         i += gridDim.x * blockDim.x) {
        if (i < W1) {
            float4 v = ((const float4*)embed)[i];
            s16x4 s = { f2bf(v.x), f2bf(v.y), f2bf(v.z), f2bf(v.w) };
            ((s16x4*)ebf)[i] = s;
        } else if (i < W2) {
            const int j = i - W1, d = j >> 14, e = j & 16383;
            float4 v = ((const float4*)(d ? Wih_b : Wih_f))[e];
            s16x4 s = { f2bf(v.x), f2bf(v.y), f2bf(v.z), f2bf(v.w) };
            ((s16x4*)wix)[d * 16384 + e] = s;
        } else {
            const int k = i - W2, d = k >> 9, c = k & 511;
            bsum[d * 512 + c] = d ? (bih_b[c] + bhh_b[c]) : (bih_f[c] + bhh_f[c]);
        }
    }
}

// ---------------- kernel 1: gx = emb(x) @ Wih^T + bias (both dirs) ----------------
// grid 2048 = B0(32) x dir(2) x tchunk(32); 8 waves; wave w = recurrence col-slot w.
// Output swizzled: gx[dt=dir*64+tile8][t][w][halflane 0..31][g 0..3][r 0..3] bf16,
// so recurrence lane l reads its 16 acc-init values as 2 coalesced dwordx4.
__global__ __launch_bounds__(512, 1) void gemm_k(
    const int* __restrict__ x, const unsigned short* __restrict__ ebf,
    const unsigned short* __restrict__ wix, const float* __restrict__ bsum,
    unsigned short* __restrict__ gx)
{
    const int tid = threadIdx.x, w = tid >> 6, l = tid & 63, qd = l >> 4, n = l & 15;
    const int bi = blockIdx.x;
    const int B0 = bi & 31, dir = (bi >> 5) & 1, tc = bi >> 6;
    const unsigned short* wr = wix + dir * 65536;

    bf16x8 bf[4][4]; float bs[4];
    #pragma unroll
    for (int g = 0; g < 4; ++g) {
        const int col = g * 128 + 16 * w + n;
        bs[g] = bsum[dir * 512 + col];
        #pragma unroll
        for (int kk = 0; kk < 4; ++kk)
            bf[g][kk] = *(const bf16x8*)(wr + (size_t)col * 128 + kk * 32 + qd * 8);
    }
    int xi[8];
    #pragma unroll
    for (int it = 0; it < 8; ++it)
        xi[it] = x[(size_t)(B0 * 16 + n) * SS + tc * 8 + it];

    const int tile8 = B0 * 2 + (qd >> 1);
    const int dt    = dir * 64 + tile8;
    const int hl    = (qd & 1) * 16 + n;

    #pragma unroll
    for (int it = 0; it < 8; ++it) {
        const int t = tc * 8 + it;
        const unsigned short* er = ebf + (size_t)xi[it] * EE;
        bf16x8 a[4];
        #pragma unroll
        for (int kk = 0; kk < 4; ++kk)
            a[kk] = *(const bf16x8*)(er + kk * 32 + qd * 8);
        f32x4 ac[4] = { {0,0,0,0}, {0,0,0,0}, {0,0,0,0}, {0,0,0,0} };
        #pragma unroll
        for (int kk = 0; kk < 4; ++kk) {
            #pragma unroll
            for (int g = 0; g < 4; ++g)
                ac[g] = __builtin_amdgcn_mfma_f32_16x16x32_bf16(a[kk], bf[g][kk], ac[g], 0, 0, 0);
        }
        char* base = (char*)gx + ((size_t)(dt * 256 + t) * 8 + w) * 1024 + hl * 32;
        #pragma unroll
        for (int g = 0; g < 4; ++g) {
            s16x4 pk = { f2bf(ac[g][0] + bs[g]), f2bf(ac[g][1] + bs[g]),
                         f2bf(ac[g][2] + bs[g]), f2bf(ac[g][3] + bs[g]) };
            *(s16x4*)(base + g * 8) = pk;
        }
    }
}

// ---------------- kernel 2: recurrence (h-half only) + fused projection ----------------
// 128 blocks (64 tiles of 8 rows x 2 dirs), 8 waves. Only Whh frags resident
// (64 VGPRs) -> total demand well under the 128-VGPR AGPR/spill cliff.
// gx streamed with 2-step register prefetch; lgkm-only barrier.
__global__ __launch_bounds__(512, 1) void lstm_k(
    const unsigned short* __restrict__ gx,
    const float* __restrict__ Whh_f, const float* __restrict__ Whh_b,
    const float* __restrict__ h0, const float* __restrict__ c0,
    const float* __restrict__ Wout,
    unsigned short* __restrict__ fpF, unsigned short* __restrict__ fpB)
{
    const int tid = threadIdx.x;
    const int w  = tid >> 6, l = tid & 63, qd = l >> 4, n = l & 15;
    const int dir = blockIdx.x & 1, tile8 = blockIdx.x >> 1;
    const int b0 = tile8 * 8, dt = dir * 64 + tile8;
    const float* Whh = dir ? Whh_b : Whh_f;
    unsigned short* fp = dir ? fpB : fpF;

    __shared__ short hbuf[2][2048];   // [octet][m 0..15][8] bf16 (rows 8-15 pad)

    bf16x8 fh[4][4];
    #pragma unroll
    for (int g = 0; g < 4; ++g) {
        const int row = g * 128 + 16 * w + n;
        #pragma unroll
        for (int kk = 0; kk < 4; ++kk) {
            const float* ph = Whh + (size_t)row * 128 + kk * 32 + qd * 8;
            bf16x8 vh;
            #pragma unroll
            for (int j = 0; j < 8; ++j) vh[j] = f2bf(ph[j]);
            fh[g][kk] = vh;
        }
    }
    bf16x8 wb[4];
    {
        const int col = (w & 3) * 16 + n;
        #pragma unroll
        for (int kk = 0; kk < 4; ++kk) {
            bf16x8 v = (bf16x8)0;
            if (col < LL) {
                const float* p = Wout + (size_t)col * 256 + dir * 128 + kk * 32 + qd * 8;
                #pragma unroll
                for (int j = 0; j < 8; ++j) v[j] = f2bf(p[j]);
            }
            wb[kk] = v;
        }
    }

    float cst[4];
    #pragma unroll
    for (int r = 0; r < 4; ++r)
        cst[r] = (qd < 2) ? c0[((size_t)dir * BB + b0 + qd * 4 + r) * HH + 16 * w + n] : 0.0f;

    {   // h0 -> hbuf[0]; pad rows zero
        const int em = l & 15, ek4 = w * 4 + qd;
        float4 hv = make_float4(0.f, 0.f, 0.f, 0.f);
        if (em < 8)
            hv = *(const float4*)(h0 + ((size_t)dir * BB + b0 + em) * HH + ek4 * 4);
        s16x4 hs = { f2bf(hv.x), f2bf(hv.y), f2bf(hv.z), f2bf(hv.w) };
        *(s16x4*)&hbuf[0][((ek4 >> 1) * 16 + em) * 8 + (ek4 & 1) * 4] = hs;
    }

    const int hl = l & 31;
    const char* gxb = (const char*)gx;
    const size_t wslab = (size_t)w * 1024 + hl * 32;
    auto gaddr = [&](int te) {
        return gxb + (size_t)(dt * 256 + te) * 8192 + wslab;
    };

    int4 a01, a23, b01, b23;
    {   // prologue: load te(0), te(1)
        const char* p0 = gaddr(dir ? SS - 1 : 0);
        a01 = *(const int4*)p0;  a23 = *(const int4*)(p0 + 16);
        const char* p1 = gaddr(dir ? SS - 2 : 1);
        b01 = *(const int4*)p1;  b23 = *(const int4*)(p1 + 16);
    }
    __syncthreads();

    const int hid = 16 * w + n, hc = hid >> 3, ho = hid & 7;

    auto step = [&](int ts, int4& u01, int4& u23) {
        const int cur = ts & 1, nxt = cur ^ 1;

        f32x4 acc[4];
        unpk(u01.x, u01.y, acc[0]); unpk(u01.z, u01.w, acc[1]);
        unpk(u23.x, u23.y, acc[2]); unpk(u23.z, u23.w, acc[3]);

        // refill u with te(ts+2): ~2 full steps to cover HBM latency
        {
            const int tf = (ts + 2 < SS) ? ts + 2 : ts;
            const char* pp = gaddr(dir ? SS - 1 - tf : tf);
            u01 = *(const int4*)pp;  u23 = *(const int4*)(pp + 16);
        }

        bf16x8 ah[4];
        #pragma unroll
        for (int kk = 0; kk < 4; ++kk)
            ah[kk] = *(const bf16x8*)&hbuf[cur][((kk * 4 + qd) * 16 + n) * 8];

        #pragma unroll
        for (int kk = 0; kk < 4; ++kk) {
            #pragma unroll
            for (int g = 0; g < 4; ++g)
                acc[g] = __builtin_amdgcn_mfma_f32_16x16x32_bf16(ah[kk], fh[g][kk], acc[g], 0, 0, 0);
        }

        if (w >= 4 && ts > 0) {   // project h_{ts-1}
            f32x4 pa = {0, 0, 0, 0};
            #pragma unroll
            for (int kk = 0; kk < 4; ++kk)
                pa = __builtin_amdgcn_mfma_f32_16x16x32_bf16(ah[kk], wb[kk], pa, 0, 0, 0);
            const int tep = dir ? (SS - ts) : (ts - 1);
            if (qd < 2) {
                #pragma unroll
                for (int r = 0; r < 4; ++r)
                    fp[((size_t)(b0 + qd * 4 + r) * SS + tep) * 64 + (w & 3) * 16 + n]
                        = (unsigned short)f2bf(pa[r]);
            }
        }

        #pragma unroll
        for (int r = 0; r < 4; ++r) {
            const float iv = sigf(acc[0][r]);
            const float fv = sigf(acc[1][r]);
            const float gv = tanhf_(acc[2][r]);
            const float ov = sigf(acc[3][r]);
            const float cc = fv * cst[r] + iv * gv;
            cst[r] = cc;
            hbuf[nxt][(hc * 16 + qd * 4 + r) * 8 + ho] = f2bf(ov * tanhf_(cc));
        }
        bar_lds();
    };

    for (int ts = 0; ts < SS; ts += 2) {
        step(ts,     a01, a23);
        step(ts + 1, b01, b23);
    }

    if (w >= 4) {   // final h projection (hbuf[0], SS even)
        f32x4 pa = {0, 0, 0, 0};
        #pragma unroll
        for (int kk = 0; kk < 4; ++kk) {
            bf16x8 a = *(const bf16x8*)&hbuf[0][((kk * 4 + qd) * 16 + n) * 8];
            pa = __builtin_amdgcn_mfma_f32_16x16x32_bf16(a, wb[kk], pa, 0, 0, 0);
        }
        const int tep = dir ? 0 : (SS - 1);
        if (qd < 2) {
            #pragma unroll
            for (int r = 0; r < 4; ++r)
                fp[((size_t)(b0 + qd * 4 + r) * SS + tep) * 64 + (w & 3) * 16 + n]
                    = (unsigned short)f2bf(pa[r]);
        }
    }
}

// ---------------- fallback recurrence (R3 path, used if ws too small) ----------------
__global__ __launch_bounds__(512, 1) void lstm_fb(
    const int* __restrict__ x, const unsigned short* __restrict__ ebf,
    const float* __restrict__ Wih_f, const float* __restrict__ Whh_f,
    const float* __restrict__ bih_f, const float* __restrict__ bhh_f,
    const float* __restrict__ Wih_b, const float* __restrict__ Whh_b,
    const float* __restrict__ bih_b, const float* __restrict__ bhh_b,
    const float* __restrict__ h0, const float* __restrict__ c0,
    const float* __restrict__ Wout,
    unsigned short* __restrict__ fpF, unsigned short* __restrict__ fpB)
{
    const int tid = threadIdx.x;
    const int w = tid >> 6, l = tid & 63, qd = l >> 4, n = l & 15;
    const int dir = blockIdx.x & 1, b0 = (blockIdx.x >> 1) * 16;
    const float* Wih = dir ? Wih_b : Wih_f;
    const float* Whh = dir ? Whh_b : Whh_f;
    const float* bih = dir ? bih_b : bih_f;
    const float* bhh = dir ? bhh_b : bhh_f;
    unsigned short* fp = dir ? fpB : fpF;

    __shared__ short hbuf[2][2048];
    __shared__ int   xsh[16 * 257];
    for (int i = tid; i < 16 * SS; i += 512)
        xsh[(i >> 8) * 257 + (i & 255)] = x[(size_t)(b0 + (i >> 8)) * SS + (i & 255)];

    bf16x8 fh[4][4], fx[4][4]; float bias[4];
    #pragma unroll
    for (int g = 0; g < 4; ++g) {
        const int row = g * 128 + 16 * w + n;
        bias[g] = bih[row] + bhh[row];
        #pragma unroll
        for (int kk = 0; kk < 4; ++kk) {
            const float* ph = Whh + (size_t)row * 128 + kk * 32 + qd * 8;
            const float* px = Wih + (size_t)row * 128 + kk * 32 + qd * 8;
            bf16x8 vh, vx;
            #pragma unroll
            for (int j = 0; j < 8; ++j) { vh[j] = f2bf(ph[j]); vx[j] = f2bf(px[j]); }
            fh[g][kk] = vh; fx[g][kk] = vx;
        }
    }
    bf16x8 wb[4];
    {
        const int col = (w & 3) * 16 + n;
        #pragma unroll
        for (int kk = 0; kk < 4; ++kk) {
            bf16x8 v = (bf16x8)0;
            if (col < LL) {
                const float* p = Wout + (size_t)col * 256 + dir * 128 + kk * 32 + qd * 8;
                #pragma unroll
                for (int j = 0; j < 8; ++j) v[j] = f2bf(p[j]);
            }
            wb[kk] = v;
        }
    }
    float cst[4];
    #pragma unroll
    for (int r = 0; r < 4; ++r)
        cst[r] = c0[((size_t)dir * BB + b0 + qd * 4 + r) * HH + 16 * w + n];
    {
        const int em = l & 15, ek4 = w * 4 + qd;
        const float4 hv = *(const float4*)(h0 + ((size_t)dir * BB + b0 + em) * HH + ek4 * 4);
        s16x4 hs = { f2bf(hv.x), f2bf(hv.y), f2bf(hv.z), f2bf(hv.w) };
        *(s16x4*)&hbuf[0][((ek4 >> 1) * 16 + em) * 8 + (ek4 & 1) * 4] = hs;
    }
    __syncthreads();
    const int hid = 16 * w + n, hc = hid >> 3, ho = hid & 7;
    bf16x8 axc[4], axn[4];
    {
        const int xi = xsh[n * 257 + (dir ? SS - 1 : 0)];
        const unsigned short* er = ebf + (size_t)xi * EE + qd * 8;
        axc[0] = *(const bf16x8*)(er);      axc[1] = *(const bf16x8*)(er + 32);
        axc[2] = *(const bf16x8*)(er + 64); axc[3] = *(const bf16x8*)(er + 96);
    }
    auto step = [&](int ts, bf16x8* axu, bf16x8* axp) {
        const int cur = ts & 1, nxt = cur ^ 1;
        {
            const int tn = (ts + 1 < SS) ? ts + 1 : ts;
            const int xi = xsh[n * 257 + (dir ? SS - 1 - tn : tn)];
            const unsigned short* er = ebf + (size_t)xi * EE + qd * 8;
            axp[0] = *(const bf16x8*)(er);      axp[1] = *(const bf16x8*)(er + 32);
            axp[2] = *(const bf16x8*)(er + 64); axp[3] = *(const bf16x8*)(er + 96);
        }
        bf16x8 ah[4];
        #pragma unroll
        for (int kk = 0; kk < 4; ++kk)
            ah[kk] = *(const bf16x8*)&hbuf[cur][((kk * 4 + qd) * 16 + n) * 8];
        f32x4 acc[4] = { {0,0,0,0}, {0,0,0,0}, {0,0,0,0}, {0,0,0,0} };
        #pragma unroll
        for (int kk = 0; kk < 4; ++kk) {
            #pragma unroll
            for (int g = 0; g < 4; ++g)
                acc[g] = __builtin_amdgcn_mfma_f32_16x16x32_bf16(axu[kk], fx[g][kk], acc[g], 0, 0, 0);
        }
        #pragma unroll
        for (int kk = 0; kk < 4; ++kk) {
            #pragma unroll
            for (int g = 0; g < 4; ++g)
                acc[g] = __builtin_amdgcn_mfma_f32_16x16x32_bf16(ah[kk], fh[g][kk], acc[g], 0, 0, 0);
        }
        if (w >= 4 && ts > 0) {
            f32x4 pa = {0, 0, 0, 0};
            #pragma unroll
            for (int kk = 0; kk < 4; ++kk)
                pa = __builtin_amdgcn_mfma_f32_16x16x32_bf16(ah[kk], wb[kk], pa, 0, 0, 0);
            const int tep = dir ? (SS - ts) : (ts - 1);
            #pragma unroll
            for (int r = 0; r < 4; ++r)
                fp[((size_t)(b0 + qd * 4 + r) * SS + tep) * 64 + (w & 3) * 16 + n]
                    = (unsigned short)f2bf(pa[r]);
        }
        #pragma unroll
        for (int r = 0; r < 4; ++r) {
            const float iv = sigf(acc[0][r] + bias[0]);
            const float fv = sigf(acc[1][r] + bias[1]);
            const float gv = tanhf_(acc[2][r] + bias[2]);
            const float ov = sigf(acc[3][r] + bias[3]);
            const float cc = fv * cst[r] + iv * gv;
            cst[r] = cc;
            hbuf[nxt][(hc * 16 + qd * 4 + r) * 8 + ho] = f2bf(ov * tanhf_(cc));
        }
        bar_lds();
    };
    for (int ts = 0; ts < SS; ts += 2) { step(ts, axc, axn); step(ts + 1, axn, axc); }
    if (w >= 4) {
        f32x4 pa = {0, 0, 0, 0};
        #pragma unroll
        for (int kk = 0; kk < 4; ++kk) {
            bf16x8 a = *(const bf16x8*)&hbuf[0][((kk * 4 + qd) * 16 + n) * 8];
            pa = __builtin_amdgcn_mfma_f32_16x16x32_bf16(a, wb[kk], pa, 0, 0, 0);
        }
        const int tep = dir ? 0 : (SS - 1);
        #pragma unroll
        for (int r = 0; r < 4; ++r)
            fp[((size_t)(b0 + qd * 4 + r) * SS + tep) * 64 + (w & 3) * 16 + n]
                = (unsigned short)f2bf(pa[r]);
    }
}

// ---------------- kernel 3: CRF forward + gold + reduce ----------------
__global__ __launch_bounds__(256, 2) void crf_k(
    const unsigned short* __restrict__ fpF, const unsigned short* __restrict__ fpB,
    const float* __restrict__ bout, const int* __restrict__ y,
    const float* __restrict__ trans, float* __restrict__ out)
{
    const int tid = threadIdx.x, w = tid >> 6, j = tid & 63;
    const int b = blockIdx.x * 4 + w;
    const size_t bS = (size_t)b * SS;
    const bool valid = (j < LL);
    const int  jr = valid ? j : (LL - 1);

    float etr[LL];
    #pragma unroll
    for (int i = 0; i < LL; ++i) {
        const float t = trans[jr * LL + i];
        etr[i] = valid ? __builtin_amdgcn_exp2f(t * 1.44269504f) : 0.0f;
    }
    const float bo = valid ? bout[jr] : 0.0f;

    float alpha = valid ? ((j == STARTL) ? 0.0f : -10000.0f) : -1e30f;

    float fF[8], fB[8];
    #pragma unroll
    for (int q = 0; q < 8; ++q) {
        fF[q] = bf2f(fpF[(bS + q) * 64 + j]);
        fB[q] = bf2f(fpB[(bS + q) * 64 + j]);
    }

    for (int t0 = 0; t0 < SS; t0 += 8) {
        float nF[8], nB[8];
        #pragma unroll
        for (int q = 0; q < 8; ++q) { nF[q] = 0.0f; nB[q] = 0.0f; }
        if (t0 + 8 < SS) {
            #pragma unroll
            for (int q = 0; q < 8; ++q) {
                nF[q] = bf2f(fpF[(bS + t0 + 8 + q) * 64 + j]);
                nB[q] = bf2f(fpB[(bS + t0 + 8 + q) * 64 + j]);
            }
        }
        #pragma unroll
        for (int u = 0; u < 8; ++u) {
            const float K = fmaxf(
                __uint_as_float(__builtin_amdgcn_readlane(__float_as_uint(alpha), 1)),
                __uint_as_float(__builtin_amdgcn_readlane(__float_as_uint(alpha), STARTL)));
            const float ea = __builtin_amdgcn_exp2f((alpha - K) * 1.44269504f);
            float d0 = 0.0f, d1 = 0.0f, d2 = 0.0f, d3 = 0.0f;
            #pragma unroll
            for (int i = 0; i < LL; i += 4) {
                d0 += etr[i] * __uint_as_float(__builtin_amdgcn_readlane(__float_as_uint(ea), i));
                if (i + 1 < LL) d1 += etr[i+1] * __uint_as_float(__builtin_amdgcn_readlane(__float_as_uint(ea), i+1));
                if (i + 2 < LL) d2 += etr[i+2] * __uint_as_float(__builtin_amdgcn_readlane(__float_as_uint(ea), i+2));
                if (i + 3 < LL) d3 += etr[i+3] * __uint_as_float(__builtin_amdgcn_readlane(__float_as_uint(ea), i+3));
            }
            const float dot = (d0 + d1) + (d2 + d3);
            alpha = (fF[u] + fB[u] + bo) + K + 0.69314718f * __builtin_amdgcn_logf(dot);
        }
        #pragma unroll
        for (int q = 0; q < 8; ++q) { fF[q] = nF[q]; fB[q] = nB[q]; }
    }

    const float v  = alpha + trans[STOPL * LL + jr];
    const float m2 = wmax64(v);
    const float s  = wsum64(__builtin_amdgcn_exp2f((v - m2) * 1.44269504f));
    const float fwd = m2 + 0.69314718f * __builtin_amdgcn_logf(s);

    float g = 0.0f;
    #pragma unroll
    for (int q = 0; q < 4; ++q) {
        const int t  = q * 64 + j;
        const int yt = y[bS + t];
        const int yp = t ? y[bS + t - 1] : STARTL;
        g += bf2f(fpF[(bS + t) * 64 + yt]) + bf2f(fpB[(bS + t) * 64 + yt])
           + bout[yt] + trans[yt * LL + yp];
    }
    g = wsum64(g);

    if (j == 0) {
        g += trans[STOPL * LL + y[bS + SS - 1]];
        atomicAdd(out, fwd - g);
    }
}

// ---------------- launcher ----------------
extern "C" void kernel_launch(void* const* d_in, const int* in_sizes, int n_in,
                              void* d_out, int out_size, void* d_ws, size_t ws_size,
                              hipStream_t stream)
{
    (void)in_sizes; (void)n_in; (void)out_size;
    const int*   x      = (const int*)  d_in[0];
    const int*   y      = (const int*)  d_in[1];
    const float* embed  = (const float*)d_in[2];
    const float* Wih_f  = (const float*)d_in[3];
    const float* Whh_f  = (const float*)d_in[4];
    const float* bih_f  = (const float*)d_in[5];
    const float* bhh_f  = (const float*)d_in[6];
    const float* Wih_b  = (const float*)d_in[7];
    const float* Whh_b  = (const float*)d_in[8];
    const float* bih_b  = (const float*)d_in[9];
    const float* bhh_b  = (const float*)d_in[10];
    const float* Wout   = (const float*)d_in[11];
    const float* bout   = (const float*)d_in[12];
    const float* trans  = (const float*)d_in[13];
    const float* h0     = (const float*)d_in[14];
    const float* c0     = (const float*)d_in[15];

    hipMemsetAsync(d_out, 0, sizeof(float), stream);
    const size_t MiB = 1ull << 20;

    if (ws_size >= 304 * MiB) {
        unsigned short* fpF  = (unsigned short*)d_ws;                          // 16 MiB
        unsigned short* fpB  = (unsigned short*)((char*)d_ws + 16 * MiB);      // 16 MiB
        unsigned short* ebf  = (unsigned short*)((char*)d_ws + 32 * MiB);      // 12.8 MB
        unsigned short* wix  = (unsigned short*)((char*)d_ws + 45 * MiB);      // 256 KiB
        float*          bsum = (float*)((char*)d_ws + (45 * MiB + 512 * 1024));// 4 KiB
        unsigned short* gx   = (unsigned short*)((char*)d_ws + 48 * MiB);      // 256 MiB

        conv_k<<<2048, 256, 0, stream>>>(embed, Wih_f, Wih_b, bih_f, bhh_f,
                                         bih_b, bhh_b, ebf, wix, bsum, 1);
        gemm_k<<<2048, 512, 0, stream>>>(x, ebf, wix, bsum, gx);
        lstm_k<<<128, 512, 0, stream>>>(gx, Whh_f, Whh_b, h0, c0, Wout, fpF, fpB);
        crf_k<<<BB / 4, 256, 0, stream>>>(fpF, fpB, bout, y, trans, (float*)d_out);
    } else {
        unsigned short* ebf = (unsigned short*)d_ws;
        unsigned short* fpF = (unsigned short*)((char*)d_ws + 16 * MiB);
        unsigned short* fpB = (unsigned short*)((char*)d_ws + 32 * MiB);

        conv_k<<<2048, 256, 0, stream>>>(embed, Wih_f, Wih_b, bih_f, bhh_f,
                                         bih_b, bhh_b, ebf, nullptr, nullptr, 0);
        lstm_fb<<<64, 512, 0, stream>>>(x, ebf, Wih_f, Whh_f, bih_f, bhh_f,
                                        Wih_b, Whh_b, bih_b, bhh_b, h0, c0,
                                        Wout, fpF, fpB);
        crf_k<<<BB / 4, 256, 0, stream>>>(fpF, fpB, bout, y, trans, (float*)d_out);
    }
}

// Round 5
// 583.693 us; speedup vs baseline: 1.0693x; 1.0693x over previous
//
#include <hip/hip_runtime.h>

// ---------------- constants ----------------
#define BB   512   // batch
#define SS   256   // seq len
#define EE   128   // emb dim
#define HH   128   // per-dir hidden
#define LL   59    // labels
#define STARTL 57
#define STOPL  58
#define VOCAB 50000

typedef float  f32x4  __attribute__((ext_vector_type(4)));
typedef short  bf16x8 __attribute__((ext_vector_type(8)));
typedef short  s16x4  __attribute__((ext_vector_type(4)));

__device__ __forceinline__ short f2bf(float f) {
    unsigned u = __float_as_uint(f);
    u += 0x7FFFu + ((u >> 16) & 1u);   // RNE
    return (short)(u >> 16);
}
__device__ __forceinline__ float bf2f(unsigned short s) {
    return __uint_as_float(((unsigned)s) << 16);
}
__device__ __forceinline__ float sigf(float x) {
    float e = __builtin_amdgcn_exp2f(-1.44269504f * x);
    return __builtin_amdgcn_rcpf(1.0f + e);
}
__device__ __forceinline__ float tanhf_(float x) {
    float e = __builtin_amdgcn_exp2f(2.88539008f * x);
    return 1.0f - 2.0f * __builtin_amdgcn_rcpf(e + 1.0f);
}
__device__ __forceinline__ float wmax64(float v) {
    #pragma unroll
    for (int o = 32; o; o >>= 1) v = fmaxf(v, __shfl_xor(v, o));
    return v;
}
__device__ __forceinline__ float wsum64(float v) {
    #pragma unroll
    for (int o = 32; o; o >>= 1) v += __shfl_xor(v, o);
    return v;
}
// LDS-only barrier: global ops stay in flight across it.
__device__ __forceinline__ void bar_lds() {
    asm volatile("s_waitcnt lgkmcnt(0)\n\ts_barrier" ::: "memory");
}
// unpack 4 packed bf16 (from 2 ints) into f32x4
__device__ __forceinline__ void unpk(int a, int b, f32x4& o) {
    o[0] = __uint_as_float((unsigned)a << 16);
    o[1] = __uint_as_float((unsigned)a & 0xFFFF0000u);
    o[2] = __uint_as_float((unsigned)b << 16);
    o[3] = __uint_as_float((unsigned)b & 0xFFFF0000u);
}

// ---------------- kernel 0: f32 -> bf16 tables + bias sums ----------------
__global__ __launch_bounds__(256) void conv_k(
    const float* __restrict__ embed,
    const float* __restrict__ Wih_f, const float* __restrict__ Wih_b,
    const float* __restrict__ Whh_f, const float* __restrict__ Whh_b,
    const float* __restrict__ bih_f, const float* __restrict__ bhh_f,
    const float* __restrict__ bih_b, const float* __restrict__ bhh_b,
    unsigned short* __restrict__ ebf, unsigned short* __restrict__ wix,
    unsigned short* __restrict__ whb, float* __restrict__ bsum)
{
    const int W1 = VOCAB * EE / 4;      // embed float4
    const int W2 = W1 + 2 * 16384;      // wix  (Wih both dirs)
    const int W3 = W2 + 2 * 16384;      // whb  (Whh both dirs)
    const int W4 = W3 + 1024;           // bias sums
    for (int i = blockIdx.x * blockDim.x + threadIdx.x; i < W4;
         i += gridDim.x * blockDim.x) {
        if (i < W1) {
            float4 v = ((const float4*)embed)[i];
            s16x4 s = { f2bf(v.x), f2bf(v.y), f2bf(v.z), f2bf(v.w) };
            ((s16x4*)ebf)[i] = s;
        } else if (i < W2) {
            const int j = i - W1, d = j >> 14, e = j & 16383;
            float4 v = ((const float4*)(d ? Wih_b : Wih_f))[e];
            s16x4 s = { f2bf(v.x), f2bf(v.y), f2bf(v.z), f2bf(v.w) };
            ((s16x4*)wix)[d * 16384 + e] = s;
        } else if (i < W3) {
            const int j = i - W2, d = j >> 14, e = j & 16383;
            float4 v = ((const float4*)(d ? Whh_b : Whh_f))[e];
            s16x4 s = { f2bf(v.x), f2bf(v.y), f2bf(v.z), f2bf(v.w) };
            ((s16x4*)whb)[d * 16384 + e] = s;
        } else {
            const int m = i - W3, d = m >> 9, c = m & 511;
            bsum[d * 512 + c] = d ? (bih_b[c] + bhh_b[c]) : (bih_f[c] + bhh_f[c]);
        }
    }
}

// ---------------- kernel 1: gx chunk = emb(x) @ Wih^T + bias ----------------
// grid = 64 dt x (CH/8); block = 8 waves; wave w = col-slot w (16 cols x 4 gates).
// Store layout: gx[s_local][dt][w][lane l][k 0..15] bf16 (k = g*4+r), so the
// recurrence lane reads its 16 acc-init values as 2 coalesced int4.
__global__ __launch_bounds__(512, 1) void gemm_k(
    const int* __restrict__ x, const unsigned short* __restrict__ ebf,
    const unsigned short* __restrict__ wix, const float* __restrict__ bsum,
    unsigned short* __restrict__ gx, int c0s)
{
    const int tid = threadIdx.x, w = tid >> 6, l = tid & 63, qd = l >> 4, n = l & 15;
    const int dt = blockIdx.x & 63, sg = blockIdx.x >> 6;
    const int btile = dt & 31, dir = dt >> 5, b0 = btile * 16;
    const unsigned short* wr = wix + dir * 65536;

    bf16x8 bf[4][4]; float bs[4];
    #pragma unroll
    for (int g = 0; g < 4; ++g) {
        const int col = g * 128 + 16 * w + n;
        bs[g] = bsum[dir * 512 + col];
        #pragma unroll
        for (int kk = 0; kk < 4; ++kk)
            bf[g][kk] = *(const bf16x8*)(wr + (size_t)col * 128 + kk * 32 + qd * 8);
    }

    #pragma unroll
    for (int it = 0; it < 8; ++it) {
        const int s_local = sg * 8 + it;
        const int gs = c0s + s_local;
        const int te = dir ? (SS - 1 - gs) : gs;
        const int xi = x[(size_t)(b0 + n) * SS + te];
        const unsigned short* er = ebf + (size_t)xi * EE;
        bf16x8 a[4];
        #pragma unroll
        for (int kk = 0; kk < 4; ++kk)
            a[kk] = *(const bf16x8*)(er + kk * 32 + qd * 8);
        f32x4 ac[4] = { {0,0,0,0}, {0,0,0,0}, {0,0,0,0}, {0,0,0,0} };
        #pragma unroll
        for (int kk = 0; kk < 4; ++kk) {
            #pragma unroll
            for (int g = 0; g < 4; ++g)
                ac[g] = __builtin_amdgcn_mfma_f32_16x16x32_bf16(a[kk], bf[g][kk], ac[g], 0, 0, 0);
        }
        char* base = (char*)gx + ((((size_t)s_local * 64 + dt) * 8 + w) * 64 + l) * 32;
        #pragma unroll
        for (int g = 0; g < 4; ++g) {
            s16x4 pk = { f2bf(ac[g][0] + bs[g]), f2bf(ac[g][1] + bs[g]),
                         f2bf(ac[g][2] + bs[g]), f2bf(ac[g][3] + bs[g]) };
            *(s16x4*)(base + g * 8) = pk;
        }
    }
}

// ---------------- kernel 2: recurrence chunk (h-half only) + fused projection ----------------
// 64 blocks (32 btiles x 2 dirs), 8 waves, 16 rows/block. Only Whh frags
// resident (64 VGPRs); Wout frags in LDS; gx streamed with 2-step register
// prefetch; lgkm-only barrier; h/c state carried across chunks in hS/cS.
__global__ __launch_bounds__(512, 1) void lstm_k(
    const unsigned short* __restrict__ gx, const unsigned short* __restrict__ whb,
    const float* __restrict__ h0, const float* __restrict__ c0,
    const float* __restrict__ Wout,
    unsigned short* __restrict__ hS, float* __restrict__ cS,
    unsigned short* __restrict__ fpF, unsigned short* __restrict__ fpB,
    int c0s, int CH)
{
    const int tid = threadIdx.x;
    const int w  = tid >> 6, l = tid & 63, qd = l >> 4, n = l & 15;
    const int dt = blockIdx.x, btile = dt & 31, dir = dt >> 5;
    const int b0 = btile * 16;
    unsigned short* fp = dir ? fpB : fpF;

    __shared__ short hbuf[2][2048];    // [octet][m 0..15][8] bf16
    __shared__ short wsh[64 * 136];    // Wout dir-half, stride 136 (pad)

    for (int i = tid; i < 64 * 128; i += 512) {
        const int col = i >> 7, k = i & 127;
        const float v = (col < LL) ? Wout[(size_t)col * 256 + dir * 128 + k] : 0.0f;
        wsh[col * 136 + k] = f2bf(v);
    }

    // Whh fragments (bf16 table): 64 VGPRs
    bf16x8 fh[4][4];
    #pragma unroll
    for (int g = 0; g < 4; ++g) {
        const int row = g * 128 + 16 * w + n;
        #pragma unroll
        for (int kk = 0; kk < 4; ++kk)
            fh[g][kk] = *(const bf16x8*)(whb + dir * 65536 + (size_t)row * 128 + kk * 32 + qd * 8);
    }

    // c state
    float cst[4];
    #pragma unroll
    for (int r = 0; r < 4; ++r) {
        const size_t idx = ((size_t)dir * BB + b0 + qd * 4 + r) * HH + 16 * w + n;
        cst[r] = (c0s == 0) ? c0[idx] : cS[idx];
    }

    // h state -> hbuf[0]
    {
        const int em = l & 15, ek4 = w * 4 + qd;
        s16x4 hs;
        if (c0s == 0) {
            const float4 hv = *(const float4*)(h0 + ((size_t)dir * BB + b0 + em) * HH + ek4 * 4);
            hs = s16x4{ f2bf(hv.x), f2bf(hv.y), f2bf(hv.z), f2bf(hv.w) };
        } else {
            hs = *(const s16x4*)(hS + ((size_t)dir * BB + b0 + em) * HH + ek4 * 4);
        }
        *(s16x4*)&hbuf[0][((ek4 >> 1) * 16 + em) * 8 + (ek4 & 1) * 4] = hs;
    }
    __syncthreads();

    const int hid = 16 * w + n, hc = hid >> 3, ho = hid & 7;
    const char* gp = (const char*)gx + (((size_t)dt * 8 + w) * 64 + l) * 32;

    int4 a01, a23, b01, b23;
    a01 = *(const int4*)gp;                a23 = *(const int4*)(gp + 16);
    b01 = *(const int4*)(gp + 1048576);    b23 = *(const int4*)(gp + 1048576 + 16);

    auto step = [&](int ts, int4& u01, int4& u23) {
        const int cur = ts & 1, nxt = cur ^ 1;
        const int gs = c0s + ts;

        f32x4 acc[4];
        unpk(u01.x, u01.y, acc[0]); unpk(u01.z, u01.w, acc[1]);
        unpk(u23.x, u23.y, acc[2]); unpk(u23.z, u23.w, acc[3]);

        {   // refill with s_local = ts+2 (clamped; dummy reload at chunk end)
            const int tf = (ts + 2 < CH) ? ts + 2 : ts;
            const char* pp = gp + (size_t)tf * 1048576;
            u01 = *(const int4*)pp;  u23 = *(const int4*)(pp + 16);
        }

        bf16x8 ah[4];
        #pragma unroll
        for (int kk = 0; kk < 4; ++kk)
            ah[kk] = *(const bf16x8*)&hbuf[cur][((kk * 4 + qd) * 16 + n) * 8];

        #pragma unroll
        for (int kk = 0; kk < 4; ++kk) {
            #pragma unroll
            for (int g = 0; g < 4; ++g)
                acc[g] = __builtin_amdgcn_mfma_f32_16x16x32_bf16(ah[kk], fh[g][kk], acc[g], 0, 0, 0);
        }

        if (w >= 4 && gs > 0) {   // project h_{gs-1} (reuses ah)
            f32x4 pa = {0, 0, 0, 0};
            #pragma unroll
            for (int kk = 0; kk < 4; ++kk) {
                const bf16x8 wfr = *(const bf16x8*)&wsh[((w & 3) * 16 + n) * 136 + kk * 32 + qd * 8];
                pa = __builtin_amdgcn_mfma_f32_16x16x32_bf16(ah[kk], wfr, pa, 0, 0, 0);
            }
            const int tep = dir ? (SS - gs) : (gs - 1);
            #pragma unroll
            for (int r = 0; r < 4; ++r)
                fp[((size_t)(b0 + qd * 4 + r) * SS + tep) * 64 + (w & 3) * 16 + n]
                    = (unsigned short)f2bf(pa[r]);
        }

        #pragma unroll
        for (int r = 0; r < 4; ++r) {
            const float iv = sigf(acc[0][r]);
            const float fv = sigf(acc[1][r]);
            const float gv = tanhf_(acc[2][r]);
            const float ov = sigf(acc[3][r]);
            const float cc = fv * cst[r] + iv * gv;
            cst[r] = cc;
            hbuf[nxt][(hc * 16 + qd * 4 + r) * 8 + ho] = f2bf(ov * tanhf_(cc));
        }
        bar_lds();
    };

    for (int ts = 0; ts < CH; ts += 2) {
        step(ts,     a01, a23);
        step(ts + 1, b01, b23);
    }
    // final h of this chunk is in hbuf[0] (CH even)

    if (c0s + CH == SS) {
        if (w >= 4) {   // project h_{SS-1}
            f32x4 pa = {0, 0, 0, 0};
            #pragma unroll
            for (int kk = 0; kk < 4; ++kk) {
                const bf16x8 a = *(const bf16x8*)&hbuf[0][((kk * 4 + qd) * 16 + n) * 8];
                const bf16x8 wfr = *(const bf16x8*)&wsh[((w & 3) * 16 + n) * 136 + kk * 32 + qd * 8];
                pa = __builtin_amdgcn_mfma_f32_16x16x32_bf16(a, wfr, pa, 0, 0, 0);
            }
            const int tep = dir ? 0 : (SS - 1);
            #pragma unroll
            for (int r = 0; r < 4; ++r)
                fp[((size_t)(b0 + qd * 4 + r) * SS + tep) * 64 + (w & 3) * 16 + n]
                    = (unsigned short)f2bf(pa[r]);
        }
    } else {
        // save state for next chunk
        const int em = l & 15, ek4 = w * 4 + qd;
        const s16x4 hs = *(const s16x4*)&hbuf[0][((ek4 >> 1) * 16 + em) * 8 + (ek4 & 1) * 4];
        *(s16x4*)(hS + ((size_t)dir * BB + b0 + em) * HH + ek4 * 4) = hs;
        #pragma unroll
        for (int r = 0; r < 4; ++r)
            cS[((size_t)dir * BB + b0 + qd * 4 + r) * HH + 16 * w + n] = cst[r];
    }
}

// ---------------- fallback recurrence (R3 path, used if ws too small) ----------------
__global__ __launch_bounds__(512, 1) void lstm_fb(
    const int* __restrict__ x, const unsigned short* __restrict__ ebf,
    const float* __restrict__ Wih_f, const float* __restrict__ Whh_f,
    const float* __restrict__ bih_f, const float* __restrict__ bhh_f,
    const float* __restrict__ Wih_b, const float* __restrict__ Whh_b,
    const float* __restrict__ bih_b, const float* __restrict__ bhh_b,
    const float* __restrict__ h0, const float* __restrict__ c0,
    const float* __restrict__ Wout,
    unsigned short* __restrict__ fpF, unsigned short* __restrict__ fpB)
{
    const int tid = threadIdx.x;
    const int w = tid >> 6, l = tid & 63, qd = l >> 4, n = l & 15;
    const int dir = blockIdx.x & 1, b0 = (blockIdx.x >> 1) * 16;
    const float* Wih = dir ? Wih_b : Wih_f;
    const float* Whh = dir ? Whh_b : Whh_f;
    const float* bih = dir ? bih_b : bih_f;
    const float* bhh = dir ? bhh_b : bhh_f;
    unsigned short* fp = dir ? fpB : fpF;

    __shared__ short hbuf[2][2048];
    __shared__ int   xsh[16 * 257];
    for (int i = tid; i < 16 * SS; i += 512)
        xsh[(i >> 8) * 257 + (i & 255)] = x[(size_t)(b0 + (i >> 8)) * SS + (i & 255)];

    bf16x8 fh[4][4], fx[4][4]; float bias[4];
    #pragma unroll
    for (int g = 0; g < 4; ++g) {
        const int row = g * 128 + 16 * w + n;
        bias[g] = bih[row] + bhh[row];
        #pragma unroll
        for (int kk = 0; kk < 4; ++kk) {
            const float* ph = Whh + (size_t)row * 128 + kk * 32 + qd * 8;
            const float* px = Wih + (size_t)row * 128 + kk * 32 + qd * 8;
            bf16x8 vh, vx;
            #pragma unroll
            for (int j = 0; j < 8; ++j) { vh[j] = f2bf(ph[j]); vx[j] = f2bf(px[j]); }
            fh[g][kk] = vh; fx[g][kk] = vx;
        }
    }
    bf16x8 wb[4];
    {
        const int col = (w & 3) * 16 + n;
        #pragma unroll
        for (int kk = 0; kk < 4; ++kk) {
            bf16x8 v = (bf16x8)0;
            if (col < LL) {
                const float* p = Wout + (size_t)col * 256 + dir * 128 + kk * 32 + qd * 8;
                #pragma unroll
                for (int j = 0; j < 8; ++j) v[j] = f2bf(p[j]);
            }
            wb[kk] = v;
        }
    }
    float cst[4];
    #pragma unroll
    for (int r = 0; r < 4; ++r)
        cst[r] = c0[((size_t)dir * BB + b0 + qd * 4 + r) * HH + 16 * w + n];
    {
        const int em = l & 15, ek4 = w * 4 + qd;
        const float4 hv = *(const float4*)(h0 + ((size_t)dir * BB + b0 + em) * HH + ek4 * 4);
        s16x4 hs = { f2bf(hv.x), f2bf(hv.y), f2bf(hv.z), f2bf(hv.w) };
        *(s16x4*)&hbuf[0][((ek4 >> 1) * 16 + em) * 8 + (ek4 & 1) * 4] = hs;
    }
    __syncthreads();
    const int hid = 16 * w + n, hc = hid >> 3, ho = hid & 7;
    bf16x8 axc[4], axn[4];
    {
        const int xi = xsh[n * 257 + (dir ? SS - 1 : 0)];
        const unsigned short* er = ebf + (size_t)xi * EE + qd * 8;
        axc[0] = *(const bf16x8*)(er);      axc[1] = *(const bf16x8*)(er + 32);
        axc[2] = *(const bf16x8*)(er + 64); axc[3] = *(const bf16x8*)(er + 96);
    }
    auto step = [&](int ts, bf16x8* axu, bf16x8* axp) {
        const int cur = ts & 1, nxt = cur ^ 1;
        {
            const int tn = (ts + 1 < SS) ? ts + 1 : ts;
            const int xi = xsh[n * 257 + (dir ? SS - 1 - tn : tn)];
            const unsigned short* er = ebf + (size_t)xi * EE + qd * 8;
            axp[0] = *(const bf16x8*)(er);      axp[1] = *(const bf16x8*)(er + 32);
            axp[2] = *(const bf16x8*)(er + 64); axp[3] = *(const bf16x8*)(er + 96);
        }
        bf16x8 ah[4];
        #pragma unroll
        for (int kk = 0; kk < 4; ++kk)
            ah[kk] = *(const bf16x8*)&hbuf[cur][((kk * 4 + qd) * 16 + n) * 8];
        f32x4 acc[4] = { {0,0,0,0}, {0,0,0,0}, {0,0,0,0}, {0,0,0,0} };
        #pragma unroll
        for (int kk = 0; kk < 4; ++kk) {
            #pragma unroll
            for (int g = 0; g < 4; ++g)
                acc[g] = __builtin_amdgcn_mfma_f32_16x16x32_bf16(axu[kk], fx[g][kk], acc[g], 0, 0, 0);
        }
        #pragma unroll
        for (int kk = 0; kk < 4; ++kk) {
            #pragma unroll
            for (int g = 0; g < 4; ++g)
                acc[g] = __builtin_amdgcn_mfma_f32_16x16x32_bf16(ah[kk], fh[g][kk], acc[g], 0, 0, 0);
        }
        if (w >= 4 && ts > 0) {
            f32x4 pa = {0, 0, 0, 0};
            #pragma unroll
            for (int kk = 0; kk < 4; ++kk)
                pa = __builtin_amdgcn_mfma_f32_16x16x32_bf16(ah[kk], wb[kk], pa, 0, 0, 0);
            const int tep = dir ? (SS - ts) : (ts - 1);
            #pragma unroll
            for (int r = 0; r < 4; ++r)
                fp[((size_t)(b0 + qd * 4 + r) * SS + tep) * 64 + (w & 3) * 16 + n]
                    = (unsigned short)f2bf(pa[r]);
        }
        #pragma unroll
        for (int r = 0; r < 4; ++r) {
            const float iv = sigf(acc[0][r] + bias[0]);
            const float fv = sigf(acc[1][r] + bias[1]);
            const float gv = tanhf_(acc[2][r] + bias[2]);
            const float ov = sigf(acc[3][r] + bias[3]);
            const float cc = fv * cst[r] + iv * gv;
            cst[r] = cc;
            hbuf[nxt][(hc * 16 + qd * 4 + r) * 8 + ho] = f2bf(ov * tanhf_(cc));
        }
        bar_lds();
    };
    for (int ts = 0; ts < SS; ts += 2) { step(ts, axc, axn); step(ts + 1, axn, axc); }
    if (w >= 4) {
        f32x4 pa = {0, 0, 0, 0};
        #pragma unroll
        for (int kk = 0; kk < 4; ++kk) {
            bf16x8 a = *(const bf16x8*)&hbuf[0][((kk * 4 + qd) * 16 + n) * 8];
            pa = __builtin_amdgcn_mfma_f32_16x16x32_bf16(a, wb[kk], pa, 0, 0, 0);
        }
        const int tep = dir ? 0 : (SS - 1);
        #pragma unroll
        for (int r = 0; r < 4; ++r)
            fp[((size_t)(b0 + qd * 4 + r) * SS + tep) * 64 + (w & 3) * 16 + n]
                = (unsigned short)f2bf(pa[r]);
    }
}

// ---------------- kernel 3: CRF forward + gold + reduce ----------------
__global__ __launch_bounds__(256, 2) void crf_k(
    const unsigned short* __restrict__ fpF, const unsigned short* __restrict__ fpB,
    const float* __restrict__ bout, const int* __restrict__ y,
    const float* __restrict__ trans, float* __restrict__ out)
{
    const int tid = threadIdx.x, w = tid >> 6, j = tid & 63;
    const int b = blockIdx.x * 4 + w;
    const size_t bS = (size_t)b * SS;
    const bool valid = (j < LL);
    const int  jr = valid ? j : (LL - 1);

    float etr[LL];
    #pragma unroll
    for (int i = 0; i < LL; ++i) {
        const float t = trans[jr * LL + i];
        etr[i] = valid ? __builtin_amdgcn_exp2f(t * 1.44269504f) : 0.0f;
    }
    const float bo = valid ? bout[jr] : 0.0f;

    float alpha = valid ? ((j == STARTL) ? 0.0f : -10000.0f) : -1e30f;

    float fF[8], fB[8];
    #pragma unroll
    for (int q = 0; q < 8; ++q) {
        fF[q] = bf2f(fpF[(bS + q) * 64 + j]);
        fB[q] = bf2f(fpB[(bS + q) * 64 + j]);
    }

    for (int t0 = 0; t0 < SS; t0 += 8) {
        float nF[8], nB[8];
        #pragma unroll
        for (int q = 0; q < 8; ++q) { nF[q] = 0.0f; nB[q] = 0.0f; }
        if (t0 + 8 < SS) {
            #pragma unroll
            for (int q = 0; q < 8; ++q) {
                nF[q] = bf2f(fpF[(bS + t0 + 8 + q) * 64 + j]);
                nB[q] = bf2f(fpB[(bS + t0 + 8 + q) * 64 + j]);
            }
        }
        #pragma unroll
        for (int u = 0; u < 8; ++u) {
            const float K = fmaxf(
                __uint_as_float(__builtin_amdgcn_readlane(__float_as_uint(alpha), 1)),
                __uint_as_float(__builtin_amdgcn_readlane(__float_as_uint(alpha), STARTL)));
            const float ea = __builtin_amdgcn_exp2f((alpha - K) * 1.44269504f);
            float d0 = 0.0f, d1 = 0.0f, d2 = 0.0f, d3 = 0.0f;
            #pragma unroll
            for (int i = 0; i < LL; i += 4) {
                d0 += etr[i] * __uint_as_float(__builtin_amdgcn_readlane(__float_as_uint(ea), i));
                if (i + 1 < LL) d1 += etr[i+1] * __uint_as_float(__builtin_amdgcn_readlane(__float_as_uint(ea), i+1));
                if (i + 2 < LL) d2 += etr[i+2] * __uint_as_float(__builtin_amdgcn_readlane(__float_as_uint(ea), i+2));
                if (i + 3 < LL) d3 += etr[i+3] * __uint_as_float(__builtin_amdgcn_readlane(__float_as_uint(ea), i+3));
            }
            const float dot = (d0 + d1) + (d2 + d3);
            alpha = (fF[u] + fB[u] + bo) + K + 0.69314718f * __builtin_amdgcn_logf(dot);
        }
        #pragma unroll
        for (int q = 0; q < 8; ++q) { fF[q] = nF[q]; fB[q] = nB[q]; }
    }

    const float v  = alpha + trans[STOPL * LL + jr];
    const float m2 = wmax64(v);
    const float s  = wsum64(__builtin_amdgcn_exp2f((v - m2) * 1.44269504f));
    const float fwd = m2 + 0.69314718f * __builtin_amdgcn_logf(s);

    float g = 0.0f;
    #pragma unroll
    for (int q = 0; q < 4; ++q) {
        const int t  = q * 64 + j;
        const int yt = y[bS + t];
        const int yp = t ? y[bS + t - 1] : STARTL;
        g += bf2f(fpF[(bS + t) * 64 + yt]) + bf2f(fpB[(bS + t) * 64 + yt])
           + bout[yt] + trans[yt * LL + yp];
    }
    g = wsum64(g);

    if (j == 0) {
        g += trans[STOPL * LL + y[bS + SS - 1]];
        atomicAdd(out, fwd - g);
    }
}

// ---------------- launcher ----------------
extern "C" void kernel_launch(void* const* d_in, const int* in_sizes, int n_in,
                              void* d_out, int out_size, void* d_ws, size_t ws_size,
                              hipStream_t stream)
{
    (void)in_sizes; (void)n_in; (void)out_size;
    const int*   x      = (const int*)  d_in[0];
    const int*   y      = (const int*)  d_in[1];
    const float* embed  = (const float*)d_in[2];
    const float* Wih_f  = (const float*)d_in[3];
    const float* Whh_f  = (const float*)d_in[4];
    const float* bih_f  = (const float*)d_in[5];
    const float* bhh_f  = (const float*)d_in[6];
    const float* Wih_b  = (const float*)d_in[7];
    const float* Whh_b  = (const float*)d_in[8];
    const float* bih_b  = (const float*)d_in[9];
    const float* bhh_b  = (const float*)d_in[10];
    const float* Wout   = (const float*)d_in[11];
    const float* bout   = (const float*)d_in[12];
    const float* trans  = (const float*)d_in[13];
    const float* h0     = (const float*)d_in[14];
    const float* c0     = (const float*)d_in[15];

    const size_t MiB = 1ull << 20;
    // workspace layout (fixed region = 48 MiB)
    unsigned short* fpF  = (unsigned short*)d_ws;                                   // 16 MiB
    unsigned short* fpB  = (unsigned short*)((char*)d_ws + 16 * MiB);               // 16 MiB
    unsigned short* ebf  = (unsigned short*)((char*)d_ws + 32 * MiB);               // 12.8 MB
    unsigned short* wix  = (unsigned short*)((char*)d_ws + 45 * MiB);               // 256 KiB
    unsigned short* whb  = (unsigned short*)((char*)d_ws + 45 * MiB + 256 * 1024);  // 256 KiB
    float*          bsum = (float*)((char*)d_ws + 45 * MiB + 512 * 1024);           // 4 KiB
    unsigned short* hS   = (unsigned short*)((char*)d_ws + 46 * MiB);               // 256 KiB
    float*          cS   = (float*)((char*)d_ws + 46 * MiB + 512 * 1024);           // 512 KiB
    unsigned short* gx   = (unsigned short*)((char*)d_ws + 48 * MiB);               // CH MiB

    const size_t avail = (ws_size > 48 * MiB) ? (ws_size - 48 * MiB) : 0;
    int NC = 0;
    if      (avail >= 256 * MiB) NC = 1;
    else if (avail >= 128 * MiB) NC = 2;
    else if (avail >=  64 * MiB) NC = 4;
    else if (avail >=  32 * MiB) NC = 8;

    hipMemsetAsync(d_out, 0, sizeof(float), stream);
    conv_k<<<2048, 256, 0, stream>>>(embed, Wih_f, Wih_b, Whh_f, Whh_b,
                                     bih_f, bhh_f, bih_b, bhh_b,
                                     ebf, wix, whb, bsum);
    if (NC) {
        const int CH = SS / NC;
        for (int c = 0; c < NC; ++c) {
            gemm_k<<<64 * (CH / 8), 512, 0, stream>>>(x, ebf, wix, bsum, gx, c * CH);
            lstm_k<<<64, 512, 0, stream>>>(gx, whb, h0, c0, Wout, hS, cS,
                                           fpF, fpB, c * CH, CH);
        }
    } else {
        lstm_fb<<<64, 512, 0, stream>>>(x, ebf, Wih_f, Whh_f, bih_f, bhh_f,
                                        Wih_b, Whh_b, bih_b, bhh_b, h0, c0,
                                        Wout, fpF, fpB);
    }
    crf_k<<<BB / 4, 256, 0, stream>>>(fpF, fpB, bout, y, trans, (float*)d_out);
}

// Round 6
// 464.053 us; speedup vs baseline: 1.3449x; 1.2578x over previous
//
#include <hip/hip_runtime.h>

// ---------------- constants ----------------
#define BB   512   // batch
#define SS   256   // seq len
#define EE   128   // emb dim
#define HH   128   // per-dir hidden
#define LL   59    // labels
#define STARTL 57
#define STOPL  58
#define VOCAB 50000

typedef float  f32x4  __attribute__((ext_vector_type(4)));
typedef short  bf16x8 __attribute__((ext_vector_type(8)));
typedef short  s16x4  __attribute__((ext_vector_type(4)));

__device__ __forceinline__ short f2bf(float f) {
    unsigned u = __float_as_uint(f);
    u += 0x7FFFu + ((u >> 16) & 1u);   // RNE
    return (short)(u >> 16);
}
__device__ __forceinline__ float bf2f(unsigned short s) {
    return __uint_as_float(((unsigned)s) << 16);
}
__device__ __forceinline__ float sigf(float x) {
    float e = __builtin_amdgcn_exp2f(-1.44269504f * x);
    return __builtin_amdgcn_rcpf(1.0f + e);
}
__device__ __forceinline__ float tanhf_(float x) {
    float e = __builtin_amdgcn_exp2f(2.88539008f * x);
    return 1.0f - 2.0f * __builtin_amdgcn_rcpf(e + 1.0f);
}
__device__ __forceinline__ float wmax64(float v) {
    #pragma unroll
    for (int o = 32; o; o >>= 1) v = fmaxf(v, __shfl_xor(v, o));
    return v;
}
__device__ __forceinline__ float wsum64(float v) {
    #pragma unroll
    for (int o = 32; o; o >>= 1) v += __shfl_xor(v, o);
    return v;
}
// LDS-only barrier: global ops stay in flight across it.
__device__ __forceinline__ void bar_lds() {
    asm volatile("s_waitcnt lgkmcnt(0)\n\ts_barrier" ::: "memory");
}

// ---------------- kernel 0: f32 -> bf16 tables + bias sums ----------------
__global__ __launch_bounds__(256) void conv_k(
    const float* __restrict__ embed,
    const float* __restrict__ Wih_f, const float* __restrict__ Wih_b,
    const float* __restrict__ Whh_f, const float* __restrict__ Whh_b,
    const float* __restrict__ bih_f, const float* __restrict__ bhh_f,
    const float* __restrict__ bih_b, const float* __restrict__ bhh_b,
    unsigned short* __restrict__ ebf, unsigned short* __restrict__ wix,
    unsigned short* __restrict__ whb, float* __restrict__ bsum)
{
    const int W1 = VOCAB * EE / 4;      // embed float4
    const int W2 = W1 + 2 * 16384;      // wix  (Wih both dirs)
    const int W3 = W2 + 2 * 16384;      // whb  (Whh both dirs)
    const int W4 = W3 + 1024;           // bias sums
    for (int i = blockIdx.x * blockDim.x + threadIdx.x; i < W4;
         i += gridDim.x * blockDim.x) {
        if (i < W1) {
            float4 v = ((const float4*)embed)[i];
            s16x4 s = { f2bf(v.x), f2bf(v.y), f2bf(v.z), f2bf(v.w) };
            ((s16x4*)ebf)[i] = s;
        } else if (i < W2) {
            const int j = i - W1, d = j >> 14, e = j & 16383;
            float4 v = ((const float4*)(d ? Wih_b : Wih_f))[e];
            s16x4 s = { f2bf(v.x), f2bf(v.y), f2bf(v.z), f2bf(v.w) };
            ((s16x4*)wix)[d * 16384 + e] = s;
        } else if (i < W3) {
            const int j = i - W2, d = j >> 14, e = j & 16383;
            float4 v = ((const float4*)(d ? Whh_b : Whh_f))[e];
            s16x4 s = { f2bf(v.x), f2bf(v.y), f2bf(v.z), f2bf(v.w) };
            ((s16x4*)whb)[d * 16384 + e] = s;
        } else {
            const int m = i - W3, d = m >> 9, c = m & 511;
            bsum[d * 512 + c] = d ? (bih_b[c] + bhh_b[c]) : (bih_f[c] + bhh_f[c]);
        }
    }
}

// ---------------- kernel 1: gx chunk = emb(x) @ Wih^T + bias ----------------
// grid = 64 x (CH/16); 16 steps per block. Store layout is per 4-row tile:
// gx[sl][dir][rt 0..127][tid 0..511][g 0..3] bf16, tid = w*64 + rowin4*16 + n,
// so a recurrence lane reads its 4 gate-init values as ONE coalesced int2.
__global__ __launch_bounds__(512, 1) void gemm_k(
    const int* __restrict__ x, const unsigned short* __restrict__ ebf,
    const unsigned short* __restrict__ wix, const float* __restrict__ bsum,
    unsigned short* __restrict__ gx, int c0s)
{
    const int tid = threadIdx.x, w = tid >> 6, l = tid & 63, qd = l >> 4, n = l & 15;
    const int dt = blockIdx.x & 63, sg = blockIdx.x >> 6;
    const int btile = dt & 31, dir = dt >> 5, b0 = btile * 16;
    const unsigned short* wr = wix + dir * 65536;

    bf16x8 bf[4][4]; float bs[4];
    #pragma unroll
    for (int g = 0; g < 4; ++g) {
        const int col = g * 128 + 16 * w + n;
        bs[g] = bsum[dir * 512 + col];
        #pragma unroll
        for (int kk = 0; kk < 4; ++kk)
            bf[g][kk] = *(const bf16x8*)(wr + (size_t)col * 128 + kk * 32 + qd * 8);
    }

    #pragma unroll 1
    for (int half = 0; half < 2; ++half) {
        int xi[8];
        #pragma unroll
        for (int it = 0; it < 8; ++it) {
            const int gs = c0s + sg * 16 + half * 8 + it;
            const int te = dir ? (SS - 1 - gs) : gs;
            xi[it] = x[(size_t)(b0 + n) * SS + te];
        }
        #pragma unroll
        for (int it = 0; it < 8; ++it) {
            const int sl = sg * 16 + half * 8 + it;
            const unsigned short* er = ebf + (size_t)xi[it] * EE;
            bf16x8 a[4];
            #pragma unroll
            for (int kk = 0; kk < 4; ++kk)
                a[kk] = *(const bf16x8*)(er + kk * 32 + qd * 8);
            f32x4 ac[4] = { {0,0,0,0}, {0,0,0,0}, {0,0,0,0}, {0,0,0,0} };
            #pragma unroll
            for (int kk = 0; kk < 4; ++kk) {
                #pragma unroll
                for (int g = 0; g < 4; ++g)
                    ac[g] = __builtin_amdgcn_mfma_f32_16x16x32_bf16(a[kk], bf[g][kk], ac[g], 0, 0, 0);
            }
            char* base = (char*)gx + (size_t)sl * 1048576
                       + (size_t)(dir * 128 + btile * 4 + qd) * 4096;
            #pragma unroll
            for (int r = 0; r < 4; ++r) {
                s16x4 pk = { f2bf(ac[0][r] + bs[0]), f2bf(ac[1][r] + bs[1]),
                             f2bf(ac[2][r] + bs[2]), f2bf(ac[3][r] + bs[3]) };
                *(s16x4*)(base + (w * 64 + r * 16 + n) * 8) = pk;
            }
        }
    }
}

// ---------------- kernel 2: recurrence, 4-row dilated tiles ----------------
// 256 blocks (128 row-tiles x 2 dirs) -> all 256 CUs. Real batch rows mapped
// to tile-rows {0,4,8,12} so only r=0 of each accumulator is real: 10 trans
// per lane per step (vs 40). Pad tile-rows stay zero. Waves 4-7 also project
// h_{t-1} against Wout (register frags). lgkm-only barrier.
__global__ __launch_bounds__(512, 1) void lstm_k(
    const unsigned short* __restrict__ gx, const unsigned short* __restrict__ whb,
    const float* __restrict__ h0, const float* __restrict__ c0,
    const float* __restrict__ Wout,
    unsigned short* __restrict__ hS, float* __restrict__ cS,
    unsigned short* __restrict__ fpF, unsigned short* __restrict__ fpB,
    int c0s, int CH)
{
    const int tid = threadIdx.x;
    const int w = tid >> 6, l = tid & 63, qd = l >> 4, n = l & 15;
    const int rt = blockIdx.x & 127, dir = blockIdx.x >> 7;
    const int b0 = rt * 4;
    unsigned short* fp = dir ? fpB : fpF;

    __shared__ short hbuf[2][2048];   // [octet][tile-row 0..15][8]; pads stay 0

    for (int i = tid; i < 1024; i += 512) ((s16x4*)hbuf)[i] = (s16x4)0;

    // Whh fragments (64 VGPRs)
    bf16x8 fh[4][4];
    #pragma unroll
    for (int g = 0; g < 4; ++g) {
        const int row = g * 128 + 16 * w + n;
        #pragma unroll
        for (int kk = 0; kk < 4; ++kk)
            fh[g][kk] = *(const bf16x8*)(whb + dir * 65536 + (size_t)row * 128 + kk * 32 + qd * 8);
    }
    // Wout fragments (16 VGPRs, waves 4-7)
    bf16x8 wb[4];
    {
        const int col = (w & 3) * 16 + n;
        #pragma unroll
        for (int kk = 0; kk < 4; ++kk) {
            bf16x8 v = (bf16x8)0;
            if (w >= 4 && col < LL) {
                const float* p = Wout + (size_t)col * 256 + dir * 128 + kk * 32 + qd * 8;
                #pragma unroll
                for (int j = 0; j < 8; ++j) v[j] = f2bf(p[j]);
            }
            wb[kk] = v;
        }
    }

    float cst;
    {
        const size_t idx = ((size_t)dir * BB + b0 + qd) * HH + 16 * w + n;
        cst = (c0s == 0) ? c0[idx] : cS[idx];
    }
    __syncthreads();   // zero-init visible before h-init overwrites

    {   // h -> hbuf[0] tile-rows {0,4,8,12}
        const int j = tid >> 7, c = tid & 127;
        short hv;
        if (c0s == 0) hv = f2bf(h0[((size_t)dir * BB + b0 + j) * HH + c]);
        else          hv = (short)hS[((size_t)dir * BB + b0 + j) * HH + c];
        hbuf[0][((c >> 3) * 16 + 4 * j) * 8 + (c & 7)] = hv;
    }
    __syncthreads();

    const int hid = 16 * w + n, hc = hid >> 3, ho = hid & 7;
    const char* gp = (const char*)gx + (size_t)(dir * 128 + rt) * 4096 + (size_t)tid * 8;

    int2 ua, ub;
    ua = *(const int2*)gp;
    ub = *(const int2*)(gp + 1048576);

    auto step = [&](int ts, int2& u) {
        const int cur = ts & 1, nxt = cur ^ 1;
        const int gs = c0s + ts;

        f32x4 acc[4] = { {0,0,0,0}, {0,0,0,0}, {0,0,0,0}, {0,0,0,0} };
        acc[0][0] = __uint_as_float((unsigned)u.x << 16);
        acc[1][0] = __uint_as_float((unsigned)u.x & 0xFFFF0000u);
        acc[2][0] = __uint_as_float((unsigned)u.y << 16);
        acc[3][0] = __uint_as_float((unsigned)u.y & 0xFFFF0000u);

        {   // refill u with step ts+2 (register prefetch; waited at use)
            const int tf = (ts + 2 < CH) ? ts + 2 : ts;
            u = *(const int2*)(gp + (size_t)tf * 1048576);
        }

        bf16x8 ah[4];
        #pragma unroll
        for (int kk = 0; kk < 4; ++kk)
            ah[kk] = *(const bf16x8*)&hbuf[cur][((kk * 4 + qd) * 16 + n) * 8];

        #pragma unroll
        for (int kk = 0; kk < 4; ++kk) {
            #pragma unroll
            for (int g = 0; g < 4; ++g)
                acc[g] = __builtin_amdgcn_mfma_f32_16x16x32_bf16(ah[kk], fh[g][kk], acc[g], 0, 0, 0);
        }

        if (w >= 4 && gs > 0) {   // project h_{gs-1} (reuses ah)
            f32x4 pa = {0, 0, 0, 0};
            #pragma unroll
            for (int kk = 0; kk < 4; ++kk)
                pa = __builtin_amdgcn_mfma_f32_16x16x32_bf16(ah[kk], wb[kk], pa, 0, 0, 0);
            const int tep = dir ? (SS - gs) : (gs - 1);
            fp[((size_t)(b0 + qd) * SS + tep) * 64 + (w & 3) * 16 + n]
                = (unsigned short)f2bf(pa[0]);
        }

        // gates: only r=0 is real (tile-row 4*qd)
        {
            const float iv = sigf(acc[0][0]);
            const float fv = sigf(acc[1][0]);
            const float gv = tanhf_(acc[2][0]);
            const float ov = sigf(acc[3][0]);
            const float cc = fv * cst + iv * gv;
            cst = cc;
            hbuf[nxt][(hc * 16 + 4 * qd) * 8 + ho] = f2bf(ov * tanhf_(cc));
        }
        bar_lds();
    };

    for (int ts = 0; ts < CH; ts += 2) {
        step(ts,     ua);
        step(ts + 1, ub);
    }

    if (c0s + CH == SS) {
        if (w >= 4) {   // project h_{SS-1} (in hbuf[0], CH even)
            f32x4 pa = {0, 0, 0, 0};
            #pragma unroll
            for (int kk = 0; kk < 4; ++kk) {
                const bf16x8 a = *(const bf16x8*)&hbuf[0][((kk * 4 + qd) * 16 + n) * 8];
                pa = __builtin_amdgcn_mfma_f32_16x16x32_bf16(a, wb[kk], pa, 0, 0, 0);
            }
            const int tep = dir ? 0 : (SS - 1);
            fp[((size_t)(b0 + qd) * SS + tep) * 64 + (w & 3) * 16 + n]
                = (unsigned short)f2bf(pa[0]);
        }
    } else {
        // carry state to next chunk
        const int j = tid >> 7, c = tid & 127;
        hS[((size_t)dir * BB + b0 + j) * HH + c] =
            (unsigned short)hbuf[0][((c >> 3) * 16 + 4 * j) * 8 + (c & 7)];
        cS[((size_t)dir * BB + b0 + qd) * HH + 16 * w + n] = cst;
    }
}

// ---------------- fallback recurrence (R3 path, tiny workspace only) ----------------
__global__ __launch_bounds__(512, 1) void lstm_fb(
    const int* __restrict__ x, const unsigned short* __restrict__ ebf,
    const float* __restrict__ Wih_f, const float* __restrict__ Whh_f,
    const float* __restrict__ bih_f, const float* __restrict__ bhh_f,
    const float* __restrict__ Wih_b, const float* __restrict__ Whh_b,
    const float* __restrict__ bih_b, const float* __restrict__ bhh_b,
    const float* __restrict__ h0, const float* __restrict__ c0,
    const float* __restrict__ Wout,
    unsigned short* __restrict__ fpF, unsigned short* __restrict__ fpB)
{
    const int tid = threadIdx.x;
    const int w = tid >> 6, l = tid & 63, qd = l >> 4, n = l & 15;
    const int dir = blockIdx.x & 1, b0 = (blockIdx.x >> 1) * 16;
    const float* Wih = dir ? Wih_b : Wih_f;
    const float* Whh = dir ? Whh_b : Whh_f;
    const float* bih = dir ? bih_b : bih_f;
    const float* bhh = dir ? bhh_b : bhh_f;
    unsigned short* fp = dir ? fpB : fpF;

    __shared__ short hbuf[2][2048];
    __shared__ int   xsh[16 * 257];
    for (int i = tid; i < 16 * SS; i += 512)
        xsh[(i >> 8) * 257 + (i & 255)] = x[(size_t)(b0 + (i >> 8)) * SS + (i & 255)];

    bf16x8 fh[4][4], fx[4][4]; float bias[4];
    #pragma unroll
    for (int g = 0; g < 4; ++g) {
        const int row = g * 128 + 16 * w + n;
        bias[g] = bih[row] + bhh[row];
        #pragma unroll
        for (int kk = 0; kk < 4; ++kk) {
            const float* ph = Whh + (size_t)row * 128 + kk * 32 + qd * 8;
            const float* px = Wih + (size_t)row * 128 + kk * 32 + qd * 8;
            bf16x8 vh, vx;
            #pragma unroll
            for (int j = 0; j < 8; ++j) { vh[j] = f2bf(ph[j]); vx[j] = f2bf(px[j]); }
            fh[g][kk] = vh; fx[g][kk] = vx;
        }
    }
    bf16x8 wb[4];
    {
        const int col = (w & 3) * 16 + n;
        #pragma unroll
        for (int kk = 0; kk < 4; ++kk) {
            bf16x8 v = (bf16x8)0;
            if (col < LL) {
                const float* p = Wout + (size_t)col * 256 + dir * 128 + kk * 32 + qd * 8;
                #pragma unroll
                for (int j = 0; j < 8; ++j) v[j] = f2bf(p[j]);
            }
            wb[kk] = v;
        }
    }
    float cst[4];
    #pragma unroll
    for (int r = 0; r < 4; ++r)
        cst[r] = c0[((size_t)dir * BB + b0 + qd * 4 + r) * HH + 16 * w + n];
    {
        const int em = l & 15, ek4 = w * 4 + qd;
        const float4 hv = *(const float4*)(h0 + ((size_t)dir * BB + b0 + em) * HH + ek4 * 4);
        s16x4 hs = { f2bf(hv.x), f2bf(hv.y), f2bf(hv.z), f2bf(hv.w) };
        *(s16x4*)&hbuf[0][((ek4 >> 1) * 16 + em) * 8 + (ek4 & 1) * 4] = hs;
    }
    __syncthreads();
    const int hid = 16 * w + n, hc = hid >> 3, ho = hid & 7;
    bf16x8 axc[4], axn[4];
    {
        const int xi = xsh[n * 257 + (dir ? SS - 1 : 0)];
        const unsigned short* er = ebf + (size_t)xi * EE + qd * 8;
        axc[0] = *(const bf16x8*)(er);      axc[1] = *(const bf16x8*)(er + 32);
        axc[2] = *(const bf16x8*)(er + 64); axc[3] = *(const bf16x8*)(er + 96);
    }
    auto step = [&](int ts, bf16x8* axu, bf16x8* axp) {
        const int cur = ts & 1, nxt = cur ^ 1;
        {
            const int tn = (ts + 1 < SS) ? ts + 1 : ts;
            const int xi = xsh[n * 257 + (dir ? SS - 1 - tn : tn)];
            const unsigned short* er = ebf + (size_t)xi * EE + qd * 8;
            axp[0] = *(const bf16x8*)(er);      axp[1] = *(const bf16x8*)(er + 32);
            axp[2] = *(const bf16x8*)(er + 64); axp[3] = *(const bf16x8*)(er + 96);
        }
        bf16x8 ah[4];
        #pragma unroll
        for (int kk = 0; kk < 4; ++kk)
            ah[kk] = *(const bf16x8*)&hbuf[cur][((kk * 4 + qd) * 16 + n) * 8];
        f32x4 acc[4] = { {0,0,0,0}, {0,0,0,0}, {0,0,0,0}, {0,0,0,0} };
        #pragma unroll
        for (int kk = 0; kk < 4; ++kk) {
            #pragma unroll
            for (int g = 0; g < 4; ++g)
                acc[g] = __builtin_amdgcn_mfma_f32_16x16x32_bf16(axu[kk], fx[g][kk], acc[g], 0, 0, 0);
        }
        #pragma unroll
        for (int kk = 0; kk < 4; ++kk) {
            #pragma unroll
            for (int g = 0; g < 4; ++g)
                acc[g] = __builtin_amdgcn_mfma_f32_16x16x32_bf16(ah[kk], fh[g][kk], acc[g], 0, 0, 0);
        }
        if (w >= 4 && ts > 0) {
            f32x4 pa = {0, 0, 0, 0};
            #pragma unroll
            for (int kk = 0; kk < 4; ++kk)
                pa = __builtin_amdgcn_mfma_f32_16x16x32_bf16(ah[kk], wb[kk], pa, 0, 0, 0);
            const int tep = dir ? (SS - ts) : (ts - 1);
            #pragma unroll
            for (int r = 0; r < 4; ++r)
                fp[((size_t)(b0 + qd * 4 + r) * SS + tep) * 64 + (w & 3) * 16 + n]
                    = (unsigned short)f2bf(pa[r]);
        }
        #pragma unroll
        for (int r = 0; r < 4; ++r) {
            const float iv = sigf(acc[0][r] + bias[0]);
            const float fv = sigf(acc[1][r] + bias[1]);
            const float gv = tanhf_(acc[2][r] + bias[2]);
            const float ov = sigf(acc[3][r] + bias[3]);
            const float cc = fv * cst[r] + iv * gv;
            cst[r] = cc;
            hbuf[nxt][(hc * 16 + qd * 4 + r) * 8 + ho] = f2bf(ov * tanhf_(cc));
        }
        bar_lds();
    };
    for (int ts = 0; ts < SS; ts += 2) { step(ts, axc, axn); step(ts + 1, axn, axc); }
    if (w >= 4) {
        f32x4 pa = {0, 0, 0, 0};
        #pragma unroll
        for (int kk = 0; kk < 4; ++kk) {
            bf16x8 a = *(const bf16x8*)&hbuf[0][((kk * 4 + qd) * 16 + n) * 8];
            pa = __builtin_amdgcn_mfma_f32_16x16x32_bf16(a, wb[kk], pa, 0, 0, 0);
        }
        const int tep = dir ? 0 : (SS - 1);
        #pragma unroll
        for (int r = 0; r < 4; ++r)
            fp[((size_t)(b0 + qd * 4 + r) * SS + tep) * 64 + (w & 3) * 16 + n]
                = (unsigned short)f2bf(pa[r]);
    }
}

// ---------------- kernel 3: CRF forward + gold + reduce ----------------
__global__ __launch_bounds__(256, 2) void crf_k(
    const unsigned short* __restrict__ fpF, const unsigned short* __restrict__ fpB,
    const float* __restrict__ bout, const int* __restrict__ y,
    const float* __restrict__ trans, float* __restrict__ out)
{
    const int tid = threadIdx.x, w = tid >> 6, j = tid & 63;
    const int b = blockIdx.x * 4 + w;
    const size_t bS = (size_t)b * SS;
    const bool valid = (j < LL);
    const int  jr = valid ? j : (LL - 1);

    float etr[LL];
    #pragma unroll
    for (int i = 0; i < LL; ++i) {
        const float t = trans[jr * LL + i];
        etr[i] = valid ? __builtin_amdgcn_exp2f(t * 1.44269504f) : 0.0f;
    }
    const float bo = valid ? bout[jr] : 0.0f;

    float alpha = valid ? ((j == STARTL) ? 0.0f : -10000.0f) : -1e30f;

    float fF[8], fB[8];
    #pragma unroll
    for (int q = 0; q < 8; ++q) {
        fF[q] = bf2f(fpF[(bS + q) * 64 + j]);
        fB[q] = bf2f(fpB[(bS + q) * 64 + j]);
    }

    for (int t0 = 0; t0 < SS; t0 += 8) {
        float nF[8], nB[8];
        #pragma unroll
        for (int q = 0; q < 8; ++q) { nF[q] = 0.0f; nB[q] = 0.0f; }
        if (t0 + 8 < SS) {
            #pragma unroll
            for (int q = 0; q < 8; ++q) {
                nF[q] = bf2f(fpF[(bS + t0 + 8 + q) * 64 + j]);
                nB[q] = bf2f(fpB[(bS + t0 + 8 + q) * 64 + j]);
            }
        }
        #pragma unroll
        for (int u = 0; u < 8; ++u) {
            const float K = fmaxf(
                __uint_as_float(__builtin_amdgcn_readlane(__float_as_uint(alpha), 1)),
                __uint_as_float(__builtin_amdgcn_readlane(__float_as_uint(alpha), STARTL)));
            const float ea = __builtin_amdgcn_exp2f((alpha - K) * 1.44269504f);
            float d0 = 0.0f, d1 = 0.0f, d2 = 0.0f, d3 = 0.0f;
            #pragma unroll
            for (int i = 0; i < LL; i += 4) {
                d0 += etr[i] * __uint_as_float(__builtin_amdgcn_readlane(__float_as_uint(ea), i));
                if (i + 1 < LL) d1 += etr[i+1] * __uint_as_float(__builtin_amdgcn_readlane(__float_as_uint(ea), i+1));
                if (i + 2 < LL) d2 += etr[i+2] * __uint_as_float(__builtin_amdgcn_readlane(__float_as_uint(ea), i+2));
                if (i + 3 < LL) d3 += etr[i+3] * __uint_as_float(__builtin_amdgcn_readlane(__float_as_uint(ea), i+3));
            }
            const float dot = (d0 + d1) + (d2 + d3);
            alpha = (fF[u] + fB[u] + bo) + K + 0.69314718f * __builtin_amdgcn_logf(dot);
        }
        #pragma unroll
        for (int q = 0; q < 8; ++q) { fF[q] = nF[q]; fB[q] = nB[q]; }
    }

    const float v  = alpha + trans[STOPL * LL + jr];
    const float m2 = wmax64(v);
    const float s  = wsum64(__builtin_amdgcn_exp2f((v - m2) * 1.44269504f));
    const float fwd = m2 + 0.69314718f * __builtin_amdgcn_logf(s);

    float g = 0.0f;
    #pragma unroll
    for (int q = 0; q < 4; ++q) {
        const int t  = q * 64 + j;
        const int yt = y[bS + t];
        const int yp = t ? y[bS + t - 1] : STARTL;
        g += bf2f(fpF[(bS + t) * 64 + yt]) + bf2f(fpB[(bS + t) * 64 + yt])
           + bout[yt] + trans[yt * LL + yp];
    }
    g = wsum64(g);

    if (j == 0) {
        g += trans[STOPL * LL + y[bS + SS - 1]];
        atomicAdd(out, fwd - g);
    }
}

// ---------------- launcher ----------------
extern "C" void kernel_launch(void* const* d_in, const int* in_sizes, int n_in,
                              void* d_out, int out_size, void* d_ws, size_t ws_size,
                              hipStream_t stream)
{
    (void)in_sizes; (void)n_in; (void)out_size;
    const int*   x      = (const int*)  d_in[0];
    const int*   y      = (const int*)  d_in[1];
    const float* embed  = (const float*)d_in[2];
    const float* Wih_f  = (const float*)d_in[3];
    const float* Whh_f  = (const float*)d_in[4];
    const float* bih_f  = (const float*)d_in[5];
    const float* bhh_f  = (const float*)d_in[6];
    const float* Wih_b  = (const float*)d_in[7];
    const float* Whh_b  = (const float*)d_in[8];
    const float* bih_b  = (const float*)d_in[9];
    const float* bhh_b  = (const float*)d_in[10];
    const float* Wout   = (const float*)d_in[11];
    const float* bout   = (const float*)d_in[12];
    const float* trans  = (const float*)d_in[13];
    const float* h0     = (const float*)d_in[14];
    const float* c0     = (const float*)d_in[15];

    const size_t MiB = 1ull << 20;
    unsigned short* fpF  = (unsigned short*)d_ws;                                   // 16 MiB
    unsigned short* fpB  = (unsigned short*)((char*)d_ws + 16 * MiB);               // 16 MiB
    unsigned short* ebf  = (unsigned short*)((char*)d_ws + 32 * MiB);               // 12.8 MB
    unsigned short* wix  = (unsigned short*)((char*)d_ws + 45 * MiB);               // 256 KiB
    unsigned short* whb  = (unsigned short*)((char*)d_ws + 45 * MiB + 256 * 1024);  // 256 KiB
    float*          bsum = (float*)((char*)d_ws + 45 * MiB + 512 * 1024);           // 4 KiB
    unsigned short* hS   = (unsigned short*)((char*)d_ws + 46 * MiB);               // 256 KiB
    float*          cS   = (float*)((char*)d_ws + 46 * MiB + 512 * 1024);           // 512 KiB
    unsigned short* gx   = (unsigned short*)((char*)d_ws + 48 * MiB);               // CH MiB

    const size_t avail = (ws_size > 48 * MiB) ? (ws_size - 48 * MiB) : 0;
    int NC = 0;
    if      (avail >= 256 * MiB) NC = 1;
    else if (avail >= 128 * MiB) NC = 2;
    else if (avail >=  64 * MiB) NC = 4;
    else if (avail >=  32 * MiB) NC = 8;

    hipMemsetAsync(d_out, 0, sizeof(float), stream);
    conv_k<<<2048, 256, 0, stream>>>(embed, Wih_f, Wih_b, Whh_f, Whh_b,
                                     bih_f, bhh_f, bih_b, bhh_b,
                                     ebf, wix, whb, bsum);
    if (NC) {
        const int CH = SS / NC;
        for (int c = 0; c < NC; ++c) {
            gemm_k<<<64 * (CH / 16), 512, 0, stream>>>(x, ebf, wix, bsum, gx, c * CH);
            lstm_k<<<256, 512, 0, stream>>>(gx, whb, h0, c0, Wout, hS, cS,
                                            fpF, fpB, c * CH, CH);
        }
    } else {
        lstm_fb<<<64, 512, 0, stream>>>(x, ebf, Wih_f, Whh_f, bih_f, bhh_f,
                                        Wih_b, Whh_b, bih_b, bhh_b, h0, c0,
                                        Wout, fpF, fpB);
    }
    crf_k<<<BB / 4, 256, 0, stream>>>(fpF, fpB, bout, y, trans, (float*)d_out);
}